// Round 6
// baseline (255.209 us; speedup 1.0000x reference)
//
#include <hip/hip_runtime.h>

#define B_    16
#define L_    2048
#define D1_   512
#define G_    2
#define V_    320
#define GV_   640
#define DG_   384
#define OUT0_ ((size_t)B_ * L_ * G_ * DG_)
#define WS_BYTES_ ((size_t)GV_ * D1_ * 2u)   // 655360: bf16-hi plane of W in frag layout
#define THR_  8e-3f

typedef __attribute__((ext_vector_type(8))) short s16x8;
typedef __attribute__((ext_vector_type(4))) float f32x4;
typedef __attribute__((ext_vector_type(4))) int   s32x4;

__device__ __forceinline__ unsigned short f2bf(float x) {
    unsigned u = __float_as_uint(x);
    u += 0x7fffu + ((u >> 16) & 1u);
    return (unsigned short)(u >> 16);
}
__device__ __forceinline__ unsigned cvtpk(float lo, float hi) {
    unsigned r;
    asm("v_cvt_pk_bf16_f32 %0, %1, %2" : "=v"(r) : "v"(lo), "v"(hi));
    return r;
}
union PU { unsigned u[4]; s16x8 v; };
__device__ __forceinline__ s16x8 pack8(const float4& a, const float4& b) {
    PU p;
    p.u[0] = cvtpk(a.x, a.y); p.u[1] = cvtpk(a.z, a.w);
    p.u[2] = cvtpk(b.x, b.y); p.u[3] = cvtpk(b.z, b.w);
    return p.v;
}
__device__ __forceinline__ void merge2(float& m1, int& i1, float& m2, int& i2,
                                       float om1, int oi1, float om2, int oi2) {
    if (om1 > m1 || (om1 == m1 && oi1 < i1)) {
        if (m1 > om2 || (m1 == om2 && i1 < oi2)) { m2 = m1; i2 = i1; }
        else                                     { m2 = om2; i2 = oi2; }
        m1 = om1; i1 = oi1;
    } else if (om1 > m2 || (om1 == m2 && oi1 < i2)) { m2 = om1; i2 = oi1; }
}

// W (640x512 fp32) -> ws: bf16 HI plane, MFMA B-frag layout.
// element (o,k): ch=o>>4, kk=k>>5, slot=(o&15)+16*((k>>3)&3), j=k&7
__global__ void prep_w_kernel(const float* __restrict__ W, unsigned short* __restrict__ ws) {
    int flat = blockIdx.x * 256 + threadIdx.x;   // 81920 threads, float4 each
    int o  = flat >> 7;
    int j0 = (flat & 127) << 2;
    float4 v = *(const float4*)(W + (size_t)o * D1_ + j0);
    int ch = o >> 4, kk = j0 >> 5;
    int slot = (o & 15) + (((j0 >> 3) & 3) << 4);
    size_t off = (((size_t)(ch * 16 + kk) * 64 + slot) << 3) + (j0 & 7);
    ws[off + 0] = f2bf(v.x); ws[off + 1] = f2bf(v.y);
    ws[off + 2] = f2bf(v.z); ws[off + 3] = f2bf(v.w);
}

// 1024 blocks = 512 l-quads x 2 groups; block: 64 rows (16b x 4l, row=li*16+b) x 320 cols.
// 8 waves = 2 rg (32 rows) x 4 cg (80 cols); per wave 2 rf x 5 cf, acc = 40 f32.
// K-loop: NO LDS, NO barriers — A gathered per-lane from global (L2), W frags from ws (L2).
template<bool HAS_WS>
__global__ __launch_bounds__(512, 4) void gvq6_kernel(
    const float* __restrict__ hidden,
    const float* __restrict__ W,
    const float* __restrict__ bias,
    const float* __restrict__ cb,
    const float* __restrict__ gn,
    float* __restrict__ out,
    const unsigned short* __restrict__ ws)
{
    __shared__ __align__(16) float pm1[4][64], pm2[4][64], plx[4][64], psum[4][64];
    __shared__ __align__(16) int   pi1[4][64], pi2[4][64];
    __shared__ int IDX[64];
    __shared__ int qn, qrow[64], qc1[64], qc2[64];

    const int tid  = threadIdx.x;
    const int w    = tid >> 6, lane = tid & 63;
    const int rg   = w >> 2, cg = w & 3;
    const int q    = lane >> 4, c = lane & 15;
    const int d    = blockIdx.x;
    const int g    = (d >> 3) & 1;
    const int lq   = (d >> 4) * 8 + (d & 7);   // XCD pairing: g=0/1 of same l-quad share XCD
    const size_t lbase = (size_t)lq * 4;

    if (tid == 0) qn = 0;

    const int arow = lane & 15;                // b for A-frag / col-low for B-frag
    const int kq8  = (lane >> 4) * 8;          // k-chunk
    const float* aP0 = hidden + ((size_t)arow * L_ + lbase + rg * 2) * D1_ + kq8;
    const float* aP1 = aP0 + D1_;
    const unsigned short* wP = ws + (size_t)(g * 20 + cg * 5) * 8192 + (size_t)lane * 8;
    const float* wfP = W + ((size_t)(g * V_ + cg * 80 + arow)) * D1_ + kq8;

    f32x4 acc0[5], acc1[5];
#pragma unroll
    for (int cf = 0; cf < 5; ++cf) { acc0[cf] = (f32x4){0,0,0,0}; acc1[cf] = (f32x4){0,0,0,0}; }

    float4 Aa0, Aa1, Aa2, Aa3, Ba0, Ba1, Ba2, Ba3;
    s16x8 Aw0, Aw1, Aw2, Aw3, Aw4, Bw0, Bw1, Bw2, Bw3, Bw4;
    s16x8 fA0, fA1, fB0, fB1;

#define LDA(S, R) { S##a0 = *(const float4*)(aP0 + (R)*32);     S##a1 = *(const float4*)(aP0 + (R)*32 + 4); \
                    S##a2 = *(const float4*)(aP1 + (R)*32);     S##a3 = *(const float4*)(aP1 + (R)*32 + 4); }
#define LDW1(S, CF, R) { if (HAS_WS) { S##w##CF = *(const s16x8*)(wP + (CF)*8192 + (R)*512); } \
                         else { float4 x_ = *(const float4*)(wfP + (CF)*8192 + (R)*32); \
                                float4 y_ = *(const float4*)(wfP + (CF)*8192 + (R)*32 + 4); \
                                S##w##CF = pack8(x_, y_); } }
#define LDW(S, R) { LDW1(S,0,R) LDW1(S,1,R) LDW1(S,2,R) LDW1(S,3,R) LDW1(S,4,R) }
#define CVT(S) { f##S##0 = pack8(S##a0, S##a1); f##S##1 = pack8(S##a2, S##a3); }
#define MM1(S, CF) { acc0[CF] = __builtin_amdgcn_mfma_f32_16x16x32_bf16(f##S##0, S##w##CF, acc0[CF], 0, 0, 0); \
                     acc1[CF] = __builtin_amdgcn_mfma_f32_16x16x32_bf16(f##S##1, S##w##CF, acc1[CF], 0, 0, 0); }
#define MM(S) { MM1(S,0) MM1(S,1) MM1(S,2) MM1(S,3) MM1(S,4) }

    LDA(A, 0) LDW(A, 0)
#pragma unroll 1
    for (int kp = 0; kp < 8; ++kp) {
        CVT(A)
        LDA(B, 1) LDW(B, 1)          // prefetch kk=2kp+1
        MM(A)                        // compute kk=2kp
        CVT(B)
        if (kp < 7) { LDA(A, 2) LDW(A, 2) }   // prefetch kk=2kp+2
        MM(B)                        // compute kk=2kp+1
        aP0 += 64; aP1 += 64; wP += 1024; wfP += 64;
    }
#undef LDA
#undef LDW1
#undef LDW
#undef CVT
#undef MM1
#undef MM

    // ---- E1: bias ----
    float bv[5];
#pragma unroll
    for (int cf = 0; cf < 5; ++cf) bv[cf] = bias[g * V_ + cg * 80 + cf * 16 + c];
#pragma unroll
    for (int cf = 0; cf < 5; ++cf)
#pragma unroll
        for (int r = 0; r < 4; ++r) { acc0[cf][r] += bv[cf]; acc1[cf][r] += bv[cf]; }

    const size_t BSTRIDE = (size_t)L_ * G_ * V_;

    // ---- E2: per-row top2(logit+gumbel) + max(logit), per cg ----
    auto scanrf = [&](const f32x4* a5, int rf) {
        const float* gbase = gn + ((((size_t)(q * 4) * L_) + lbase + rg * 2 + rf) * G_ + g) * V_
                               + cg * 80 + c;
        float m1[4], m2[4], lx[4]; int i1[4], i2[4];
#pragma unroll
        for (int r = 0; r < 4; ++r) { m1[r] = -3e38f; m2[r] = -3e38f; lx[r] = -3e38f; i1[r] = 0; i2[r] = 0; }
#pragma unroll
        for (int cf = 0; cf < 5; ++cf) {
            const int col = cg * 80 + cf * 16 + c;
#pragma unroll
            for (int r = 0; r < 4; ++r) {
                float lg = a5[cf][r];
                float s  = lg + __builtin_nontemporal_load(gbase + (size_t)r * BSTRIDE + cf * 16);
                lx[r] = fmaxf(lx[r], lg);
                if (s > m1[r])      { m2[r] = m1[r]; i2[r] = i1[r]; m1[r] = s; i1[r] = col; }
                else if (s > m2[r]) { m2[r] = s; i2[r] = col; }
            }
        }
#pragma unroll
        for (int mk = 1; mk <= 8; mk <<= 1) {
#pragma unroll
            for (int r = 0; r < 4; ++r) {
                float om1 = __shfl_xor(m1[r], mk); int oi1 = __shfl_xor(i1[r], mk);
                float om2 = __shfl_xor(m2[r], mk); int oi2 = __shfl_xor(i2[r], mk);
                lx[r] = fmaxf(lx[r], __shfl_xor(lx[r], mk));
                merge2(m1[r], i1[r], m2[r], i2[r], om1, oi1, om2, oi2);
            }
        }
        if (c == 0) {
            int row0 = rg * 32 + rf * 16 + q * 4;
            *(f32x4*)&pm1[cg][row0] = (f32x4){m1[0], m1[1], m1[2], m1[3]};
            *(s32x4*)&pi1[cg][row0] = (s32x4){i1[0], i1[1], i1[2], i1[3]};
            *(f32x4*)&pm2[cg][row0] = (f32x4){m2[0], m2[1], m2[2], m2[3]};
            *(s32x4*)&pi2[cg][row0] = (s32x4){i2[0], i2[1], i2[2], i2[3]};
            *(f32x4*)&plx[cg][row0] = (f32x4){lx[0], lx[1], lx[2], lx[3]};
        }
    };
    scanrf(acc0, 0);
    scanrf(acc1, 1);
    __syncthreads();

    // ---- E3a: row max -> exp -> row sum ----
    auto softrf = [&](f32x4* a5, int rf) {
        int row0 = rg * 32 + rf * 16 + q * 4;
        float LM[4], se[4];
#pragma unroll
        for (int r = 0; r < 4; ++r) {
            LM[r] = fmaxf(fmaxf(plx[0][row0 + r], plx[1][row0 + r]),
                          fmaxf(plx[2][row0 + r], plx[3][row0 + r]));
            se[r] = 0.f;
        }
#pragma unroll
        for (int cf = 0; cf < 5; ++cf)
#pragma unroll
            for (int r = 0; r < 4; ++r) {
                float e = __expf(a5[cf][r] - LM[r]);
                a5[cf][r] = e; se[r] += e;
            }
#pragma unroll
        for (int mk = 1; mk <= 8; mk <<= 1)
#pragma unroll
            for (int r = 0; r < 4; ++r) se[r] += __shfl_xor(se[r], mk);
        if (c == 0) *(f32x4*)&psum[cg][row0] = (f32x4){se[0], se[1], se[2], se[3]};
    };
    softrf(acc0, 0);
    softrf(acc1, 1);
    __syncthreads();

    // ---- E3b: scale, b-sum, direct nt perp store ----
    auto perprf = [&](const f32x4* a5, int rf) {
        int row0 = rg * 32 + rf * 16 + q * 4;
        float IZ[4];
#pragma unroll
        for (int r = 0; r < 4; ++r)
            IZ[r] = 1.0f / ((psum[0][row0 + r] + psum[1][row0 + r]
                           + psum[2][row0 + r] + psum[3][row0 + r]) * 16.0f);
        size_t ob = OUT0_ + (lbase + rg * 2 + rf) * GV_ + g * V_ + cg * 80 + c;
#pragma unroll
        for (int cf = 0; cf < 5; ++cf) {
            float pp = a5[cf][0] * IZ[0] + a5[cf][1] * IZ[1]
                     + a5[cf][2] * IZ[2] + a5[cf][3] * IZ[3];
            pp += __shfl_xor(pp, 16); pp += __shfl_xor(pp, 32);
            if (q == 0) __builtin_nontemporal_store(pp, &out[ob + cf * 16]);
        }
    };
    perprf(acc0, 0);
    perprf(acc1, 1);

    // ---- E6: argmax finalize; queue near-ties for wave-parallel fp64 refine ----
    if (tid < 64) {
        const int row = tid;
        float M1 = pm1[0][row]; int I1 = pi1[0][row];
        float M2 = pm2[0][row]; int I2 = pi2[0][row];
#pragma unroll
        for (int c2 = 1; c2 < 4; ++c2)
            merge2(M1, I1, M2, I2, pm1[c2][row], pi1[c2][row], pm2[c2][row], pi2[c2][row]);
        if (M1 - M2 >= THR_) {
            IDX[row] = I1;
        } else {
            int s = atomicAdd(&qn, 1);
            qrow[s] = row; qc1[s] = I1; qc2[s] = I2;
        }
    }
    __syncthreads();

    // ---- refine: one wave per queued row; lanes split k; fp64 exact top-2 compare ----
    {
        const int nq = qn;
        for (int qi = w; qi < nq; qi += 8) {
            const int row = qrow[qi];
            const int c1 = qc1[qi], c2 = qc2[qi];
            const int b = row & 15, li = row >> 4;
            const float* ar = hidden + ((size_t)b * L_ + lbase + li) * D1_ + lane * 8;
            const float* w1 = W + (size_t)(g * V_ + c1) * D1_ + lane * 8;
            const float* w2 = W + (size_t)(g * V_ + c2) * D1_ + lane * 8;
            double s1 = 0.0, s2 = 0.0;
#pragma unroll
            for (int j = 0; j < 8; ++j) {
                double a = (double)ar[j];
                s1 = fma(a, (double)w1[j], s1);
                s2 = fma(a, (double)w2[j], s2);
            }
#pragma unroll
            for (int off = 1; off < 64; off <<= 1) {
                s1 += __shfl_xor(s1, off);
                s2 += __shfl_xor(s2, off);
            }
            if (lane == 0) {
                const size_t gb = (((size_t)b * L_ + lbase + li) * G_ + g) * V_;
                s1 += (double)bias[g * V_ + c1] + (double)gn[gb + c1];
                s2 += (double)bias[g * V_ + c2] + (double)gn[gb + c2];
                IDX[row] = (s2 > s1 || (s2 == s1 && c2 < c1)) ? c2 : c1;
            }
        }
    }
    __syncthreads();

    // ---- E7: code-vector gather, nt stores ----
#pragma unroll 1
    for (int it = 0; it < 12; ++it) {
        int i = tid + it * 512;                 // 0..6143 float4-tasks (64 rows x 96)
        int row = i / 96, f = i - row * 96;
        int v = IDX[row];
        int b = row & 15, li = row >> 4;
        f32x4 val = *(const f32x4*)(cb + ((size_t)(g * V_ + v) * DG_) + f * 4);
        __builtin_nontemporal_store(val,
            (f32x4*)(out + ((size_t)b * L_ + lbase + li) * (G_ * DG_) + g * DG_ + f * 4));
    }
}

extern "C" void kernel_launch(void* const* d_in, const int* in_sizes, int n_in,
                              void* d_out, int out_size, void* d_ws, size_t ws_size,
                              hipStream_t stream) {
    const float* hidden   = (const float*)d_in[0];
    const float* W        = (const float*)d_in[1];
    const float* bias     = (const float*)d_in[2];
    const float* codebook = (const float*)d_in[3];
    const float* gumbel   = (const float*)d_in[4];
    float* out = (float*)d_out;

    if (ws_size >= WS_BYTES_) {
        prep_w_kernel<<<320, 256, 0, stream>>>(W, (unsigned short*)d_ws);
        gvq6_kernel<true><<<1024, 512, 0, stream>>>(hidden, W, bias, codebook, gumbel, out,
                                                    (const unsigned short*)d_ws);
    } else {
        gvq6_kernel<false><<<1024, 512, 0, stream>>>(hidden, W, bias, codebook, gumbel, out,
                                                     (const unsigned short*)d_ws);
    }
}

// Round 8
// 207.977 us; speedup vs baseline: 1.2271x; 1.2271x over previous
//
#include <hip/hip_runtime.h>

#define B_    16
#define L_    2048
#define D1_   512
#define G_    2
#define V_    320
#define GV_   640
#define DG_   384
#define OUT0_ ((size_t)B_ * L_ * G_ * DG_)
#define WS_BYTES_ ((size_t)GV_ * D1_ * 2u)   // 655360: bf16-hi plane of W in frag layout
#define THR_  8e-3f
#define GPAD_ 324

typedef __attribute__((ext_vector_type(8))) short s16x8;
typedef __attribute__((ext_vector_type(4))) float f32x4;
typedef __attribute__((ext_vector_type(4))) int   s32x4;

__device__ __forceinline__ unsigned short f2bf(float x) {
    unsigned u = __float_as_uint(x);
    u += 0x7fffu + ((u >> 16) & 1u);
    return (unsigned short)(u >> 16);
}
__device__ __forceinline__ unsigned cvtpk(float lo, float hi) {
    unsigned r;
    asm("v_cvt_pk_bf16_f32 %0, %1, %2" : "=v"(r) : "v"(lo), "v"(hi));
    return r;
}
union PU { unsigned u[4]; s16x8 v; };
__device__ __forceinline__ s16x8 pack8(const float4& a, const float4& b) {
    PU p;
    p.u[0] = cvtpk(a.x, a.y); p.u[1] = cvtpk(a.z, a.w);
    p.u[2] = cvtpk(b.x, b.y); p.u[3] = cvtpk(b.z, b.w);
    return p.v;
}
__device__ __forceinline__ void merge2(float& m1, int& i1, float& m2, int& i2,
                                       float om1, int oi1, float om2, int oi2) {
    if (om1 > m1 || (om1 == m1 && oi1 < i1)) {
        if (m1 > om2 || (m1 == om2 && i1 < oi2)) { m2 = m1; i2 = i1; }
        else                                     { m2 = om2; i2 = oi2; }
        m1 = om1; i1 = oi1;
    } else if (om1 > m2 || (om1 == m2 && oi1 < i2)) { m2 = om1; i2 = oi1; }
}

// W (640x512 fp32) -> ws: bf16 HI plane, MFMA B-frag layout.
__global__ void prep_w_kernel(const float* __restrict__ W, unsigned short* __restrict__ ws) {
    int flat = blockIdx.x * 256 + threadIdx.x;   // 81920 threads, float4 each
    int o  = flat >> 7;
    int j0 = (flat & 127) << 2;
    float4 v = *(const float4*)(W + (size_t)o * D1_ + j0);
    int ch = o >> 4, kk = j0 >> 5;
    int slot = (o & 15) + (((j0 >> 3) & 3) << 4);
    size_t off = (((size_t)(ch * 16 + kk) * 64 + slot) << 3) + (j0 & 7);
    ws[off + 0] = f2bf(v.x); ws[off + 1] = f2bf(v.y);
    ws[off + 2] = f2bf(v.z); ws[off + 3] = f2bf(v.w);
}

// 1024 blocks = 512 l-quads x 2 groups; block: 64 rows (16b x 4l, row=li*16+b) x 320 cols.
// 8 waves = 2 rg x 4 cg; per wave 2 rf x 5 cf, acc = 40 f32.
// K-loop: NO LDS, NO barriers. Epilogue: gn staged via LDS, coalesced (r6 lesson:
// scattered scalar gn reads of the 80 MB gumbel stream dominated the kernel).
template<bool HAS_WS>
__global__ __launch_bounds__(512, 4) void gvq7_kernel(
    const float* __restrict__ hidden,
    const float* __restrict__ W,
    const float* __restrict__ bias,
    const float* __restrict__ cb,
    const float* __restrict__ gn,
    float* __restrict__ out,
    const unsigned short* __restrict__ ws)
{
    __shared__ float GLDS[32][GPAD_];            // 41.5 KB gn tile (one rf-pass: 32 rows x 320)
    __shared__ __align__(16) float pm1[4][64], pm2[4][64], plx[4][64], psum[4][64];
    __shared__ __align__(16) int   pi1[4][64], pi2[4][64];
    __shared__ int IDX[64];
    __shared__ int qn, qrow[64], qc1[64], qc2[64];

    const int tid  = threadIdx.x;
    const int w    = tid >> 6, lane = tid & 63;
    const int rg   = w >> 2, cg = w & 3;
    const int q    = lane >> 4, c = lane & 15;
    const int d    = blockIdx.x;
    const int g    = (d >> 3) & 1;
    const int lq   = (d >> 4) * 8 + (d & 7);   // XCD pairing: g=0/1 of same l-quad share XCD
    const size_t lbase = (size_t)lq * 4;

    if (tid == 0) qn = 0;

    const int arow = lane & 15;                // b for A-frag / col-low for B-frag
    const int kq8  = (lane >> 4) * 8;          // k-chunk
    const float* aP0 = hidden + ((size_t)arow * L_ + lbase + rg * 2) * D1_ + kq8;
    const float* aP1 = aP0 + D1_;
    const unsigned short* wP = ws + (size_t)(g * 20 + cg * 5) * 8192 + (size_t)lane * 8;
    const float* wfP = W + ((size_t)(g * V_ + cg * 80 + arow)) * D1_ + kq8;

    // gn staging map: 16 threads per row; srow = rg_s*16 + b, pass p -> l = lbase + 2*rg_s + p
    const int srow = tid >> 4, t16 = tid & 15;
    const float* gnst = gn + (((size_t)(srow & 15) * L_ + lbase + ((srow >> 4) << 1)) * G_ + g) * V_
                           + (t16 << 2);

    f32x4 acc0[5], acc1[5];
#pragma unroll
    for (int cf = 0; cf < 5; ++cf) { acc0[cf] = (f32x4){0,0,0,0}; acc1[cf] = (f32x4){0,0,0,0}; }

    float4 Aa0, Aa1, Aa2, Aa3, Ba0, Ba1, Ba2, Ba3;
    s16x8 Aw0, Aw1, Aw2, Aw3, Aw4, Bw0, Bw1, Bw2, Bw3, Bw4;
    s16x8 fA0, fA1, fB0, fB1;

#define LDA(S, R) { S##a0 = *(const float4*)(aP0 + (R)*32);     S##a1 = *(const float4*)(aP0 + (R)*32 + 4); \
                    S##a2 = *(const float4*)(aP1 + (R)*32);     S##a3 = *(const float4*)(aP1 + (R)*32 + 4); }
#define LDW1(S, CF, R) { if (HAS_WS) { S##w##CF = *(const s16x8*)(wP + (CF)*8192 + (R)*512); } \
                         else { float4 x_ = *(const float4*)(wfP + (CF)*8192 + (R)*32); \
                                float4 y_ = *(const float4*)(wfP + (CF)*8192 + (R)*32 + 4); \
                                S##w##CF = pack8(x_, y_); } }
#define LDW(S, R) { LDW1(S,0,R) LDW1(S,1,R) LDW1(S,2,R) LDW1(S,3,R) LDW1(S,4,R) }
#define CVT(S) { f##S##0 = pack8(S##a0, S##a1); f##S##1 = pack8(S##a2, S##a3); }
#define MM1(S, CF) { acc0[CF] = __builtin_amdgcn_mfma_f32_16x16x32_bf16(f##S##0, S##w##CF, acc0[CF], 0, 0, 0); \
                     acc1[CF] = __builtin_amdgcn_mfma_f32_16x16x32_bf16(f##S##1, S##w##CF, acc1[CF], 0, 0, 0); }
#define MM(S) { MM1(S,0) MM1(S,1) MM1(S,2) MM1(S,3) MM1(S,4) }

    LDA(A, 0) LDW(A, 0)
#pragma unroll 1
    for (int kp = 0; kp < 8; ++kp) {
        CVT(A)
        LDA(B, 1) LDW(B, 1)          // prefetch kk=2kp+1
        MM(A)                        // compute kk=2kp
        CVT(B)
        if (kp < 7) { LDA(A, 2) LDW(A, 2) }   // prefetch kk=2kp+2
        MM(B)                        // compute kk=2kp+1
        aP0 += 64; aP1 += 64; wP += 1024; wfP += 64;
    }
#undef LDA
#undef LDW1
#undef LDW
#undef CVT
#undef MM1
#undef MM

    // ---- E1: bias ----
    float bv[5];
#pragma unroll
    for (int cf = 0; cf < 5; ++cf) bv[cf] = bias[g * V_ + cg * 80 + cf * 16 + c];
#pragma unroll
    for (int cf = 0; cf < 5; ++cf)
#pragma unroll
        for (int r = 0; r < 4; ++r) { acc0[cf][r] += bv[cf]; acc1[cf][r] += bv[cf]; }

    // ---- E2: per-row top2(logit+gumbel) + max(logit); gn via coalesced LDS passes ----
    auto scanrf = [&](const f32x4* a5, int rf) {
        float m1[4], m2[4], lx[4]; int i1[4], i2[4];
#pragma unroll
        for (int r = 0; r < 4; ++r) { m1[r] = -3e38f; m2[r] = -3e38f; lx[r] = -3e38f; i1[r] = 0; i2[r] = 0; }
#pragma unroll
        for (int cf = 0; cf < 5; ++cf) {
            const int col = cg * 80 + cf * 16 + c;
#pragma unroll
            for (int r = 0; r < 4; ++r) {
                float lg = a5[cf][r];
                float s  = lg + GLDS[rg * 16 + q * 4 + r][col];
                lx[r] = fmaxf(lx[r], lg);
                if (s > m1[r])      { m2[r] = m1[r]; i2[r] = i1[r]; m1[r] = s; i1[r] = col; }
                else if (s > m2[r]) { m2[r] = s; i2[r] = col; }
            }
        }
#pragma unroll
        for (int mk = 1; mk <= 8; mk <<= 1) {
#pragma unroll
            for (int r = 0; r < 4; ++r) {
                float om1 = __shfl_xor(m1[r], mk); int oi1 = __shfl_xor(i1[r], mk);
                float om2 = __shfl_xor(m2[r], mk); int oi2 = __shfl_xor(i2[r], mk);
                lx[r] = fmaxf(lx[r], __shfl_xor(lx[r], mk));
                merge2(m1[r], i1[r], m2[r], i2[r], om1, oi1, om2, oi2);
            }
        }
        if (c == 0) {
            int row0 = rg * 32 + rf * 16 + q * 4;
            *(f32x4*)&pm1[cg][row0] = (f32x4){m1[0], m1[1], m1[2], m1[3]};
            *(s32x4*)&pi1[cg][row0] = (s32x4){i1[0], i1[1], i1[2], i1[3]};
            *(f32x4*)&pm2[cg][row0] = (f32x4){m2[0], m2[1], m2[2], m2[3]};
            *(s32x4*)&pi2[cg][row0] = (s32x4){i2[0], i2[1], i2[2], i2[3]};
            *(f32x4*)&plx[cg][row0] = (f32x4){lx[0], lx[1], lx[2], lx[3]};
        }
    };

    {   // pass 0 (rf=0 rows)
        f32x4 gr[5];
#pragma unroll
        for (int j = 0; j < 5; ++j)
            gr[j] = __builtin_nontemporal_load((const f32x4*)(gnst + j * 64));
#pragma unroll
        for (int j = 0; j < 5; ++j)
            *(f32x4*)&GLDS[srow][(t16 << 2) + j * 64] = gr[j];
        __syncthreads();
        scanrf(acc0, 0);
        __syncthreads();
    }
    {   // pass 1 (rf=1 rows)
        f32x4 gr[5];
#pragma unroll
        for (int j = 0; j < 5; ++j)
            gr[j] = __builtin_nontemporal_load((const f32x4*)(gnst + GV_ + j * 64));
#pragma unroll
        for (int j = 0; j < 5; ++j)
            *(f32x4*)&GLDS[srow][(t16 << 2) + j * 64] = gr[j];
        __syncthreads();
        scanrf(acc1, 1);
        __syncthreads();
    }

    // ---- E3a: row max -> exp -> row sum ----
    auto softrf = [&](f32x4* a5, int rf) {
        int row0 = rg * 32 + rf * 16 + q * 4;
        float LM[4], se[4];
#pragma unroll
        for (int r = 0; r < 4; ++r) {
            LM[r] = fmaxf(fmaxf(plx[0][row0 + r], plx[1][row0 + r]),
                          fmaxf(plx[2][row0 + r], plx[3][row0 + r]));
            se[r] = 0.f;
        }
#pragma unroll
        for (int cf = 0; cf < 5; ++cf)
#pragma unroll
            for (int r = 0; r < 4; ++r) {
                float e = __expf(a5[cf][r] - LM[r]);
                a5[cf][r] = e; se[r] += e;
            }
#pragma unroll
        for (int mk = 1; mk <= 8; mk <<= 1)
#pragma unroll
            for (int r = 0; r < 4; ++r) se[r] += __shfl_xor(se[r], mk);
        if (c == 0) *(f32x4*)&psum[cg][row0] = (f32x4){se[0], se[1], se[2], se[3]};
    };
    softrf(acc0, 0);
    softrf(acc1, 1);
    __syncthreads();

    // ---- E3b: scale, b-sum, direct nt perp store ----
    auto perprf = [&](const f32x4* a5, int rf) {
        int row0 = rg * 32 + rf * 16 + q * 4;
        float IZ[4];
#pragma unroll
        for (int r = 0; r < 4; ++r)
            IZ[r] = 1.0f / ((psum[0][row0 + r] + psum[1][row0 + r]
                           + psum[2][row0 + r] + psum[3][row0 + r]) * 16.0f);
        size_t ob = OUT0_ + (lbase + rg * 2 + rf) * GV_ + g * V_ + cg * 80 + c;
#pragma unroll
        for (int cf = 0; cf < 5; ++cf) {
            float pp = a5[cf][0] * IZ[0] + a5[cf][1] * IZ[1]
                     + a5[cf][2] * IZ[2] + a5[cf][3] * IZ[3];
            pp += __shfl_xor(pp, 16); pp += __shfl_xor(pp, 32);
            if (q == 0) __builtin_nontemporal_store(pp, &out[ob + cf * 16]);
        }
    };
    perprf(acc0, 0);
    perprf(acc1, 1);

    // ---- E6: argmax finalize; queue near-ties for wave-parallel fp64 refine ----
    if (tid < 64) {
        const int row = tid;
        float M1 = pm1[0][row]; int I1 = pi1[0][row];
        float M2 = pm2[0][row]; int I2 = pi2[0][row];
#pragma unroll
        for (int c2 = 1; c2 < 4; ++c2)
            merge2(M1, I1, M2, I2, pm1[c2][row], pi1[c2][row], pm2[c2][row], pi2[c2][row]);
        if (M1 - M2 >= THR_) {
            IDX[row] = I1;
        } else {
            int s = atomicAdd(&qn, 1);
            qrow[s] = row; qc1[s] = I1; qc2[s] = I2;
        }
    }
    __syncthreads();

    // ---- refine: one wave per queued row; lanes split k; fp64 exact top-2 compare ----
    {
        const int nq = qn;
        for (int qi = w; qi < nq; qi += 8) {
            const int row = qrow[qi];
            const int c1 = qc1[qi], c2 = qc2[qi];
            const int b = row & 15, li = row >> 4;
            const float* ar = hidden + ((size_t)b * L_ + lbase + li) * D1_ + lane * 8;
            const float* w1 = W + (size_t)(g * V_ + c1) * D1_ + lane * 8;
            const float* w2 = W + (size_t)(g * V_ + c2) * D1_ + lane * 8;
            double s1 = 0.0, s2 = 0.0;
#pragma unroll
            for (int j = 0; j < 8; ++j) {
                double a = (double)ar[j];
                s1 = fma(a, (double)w1[j], s1);
                s2 = fma(a, (double)w2[j], s2);
            }
#pragma unroll
            for (int off = 1; off < 64; off <<= 1) {
                s1 += __shfl_xor(s1, off);
                s2 += __shfl_xor(s2, off);
            }
            if (lane == 0) {
                const size_t gb = (((size_t)b * L_ + lbase + li) * G_ + g) * V_;
                s1 += (double)bias[g * V_ + c1] + (double)gn[gb + c1];
                s2 += (double)bias[g * V_ + c2] + (double)gn[gb + c2];
                IDX[row] = (s2 > s1 || (s2 == s1 && c2 < c1)) ? c2 : c1;
            }
        }
    }
    __syncthreads();

    // ---- E7: code-vector gather, nt stores ----
#pragma unroll 1
    for (int it = 0; it < 12; ++it) {
        int i = tid + it * 512;                 // 0..6143 float4-tasks (64 rows x 96)
        int row = i / 96, f = i - row * 96;
        int v = IDX[row];
        int b = row & 15, li = row >> 4;
        f32x4 val = *(const f32x4*)(cb + ((size_t)(g * V_ + v) * DG_) + f * 4);
        __builtin_nontemporal_store(val,
            (f32x4*)(out + ((size_t)b * L_ + lbase + li) * (G_ * DG_) + g * DG_ + f * 4));
    }
}

extern "C" void kernel_launch(void* const* d_in, const int* in_sizes, int n_in,
                              void* d_out, int out_size, void* d_ws, size_t ws_size,
                              hipStream_t stream) {
    const float* hidden   = (const float*)d_in[0];
    const float* W        = (const float*)d_in[1];
    const float* bias     = (const float*)d_in[2];
    const float* codebook = (const float*)d_in[3];
    const float* gumbel   = (const float*)d_in[4];
    float* out = (float*)d_out;

    if (ws_size >= WS_BYTES_) {
        prep_w_kernel<<<320, 256, 0, stream>>>(W, (unsigned short*)d_ws);
        gvq7_kernel<true><<<1024, 512, 0, stream>>>(hidden, W, bias, codebook, gumbel, out,
                                                    (const unsigned short*)d_ws);
    } else {
        gvq7_kernel<false><<<1024, 512, 0, stream>>>(hidden, W, bias, codebook, gumbel, out,
                                                     (const unsigned short*)d_ws);
    }
}